// Round 1
// baseline (1185.009 us; speedup 1.0000x reference)
//
#include <hip/hip_runtime.h>
#include <hip/hip_bf16.h>
#include <math.h>

#define BATCH 4096
#define HID 256
#define NG 1024   // 4*HID
#define OBS_D 400
#define OUT_W 15

__device__ __forceinline__ float sigf(float x) { return 1.0f / (1.0f + __expf(-x)); }
__device__ __forceinline__ float tanh_fast(float x) { return 1.0f - 2.0f / (__expf(2.0f * x) + 1.0f); }

// ---------------------------------------------------------------------------
// Prep: weight transposes + per-step fused biases + samp gather tables
// ---------------------------------------------------------------------------
__global__ __launch_bounds__(256) void prep_kernel(
    const float* __restrict__ W_ih, const float* __restrict__ W_hh,
    const float* __restrict__ b_ih, const float* __restrict__ b_hh,
    const float* __restrict__ addr_emb, const float* __restrict__ pid_emb,
    const float* __restrict__ sid_emb,
    const float* __restrict__ mlp_w2, const float* __restrict__ mlp_w3,
    float* __restrict__ W_ih_T, float* __restrict__ W_hh_T,
    float* __restrict__ bias_all, float* __restrict__ pid_rows,
    float* __restrict__ sid_rows, float* __restrict__ w2t, float* __restrict__ w3t)
{
    int blk = blockIdx.x, t = threadIdx.x;
    if (blk < 112) {
        // W_ih (1024x432) -> W_ih_T (432x1024), 64x64 tiles (16 j-tiles x 7 k-tiles)
        __shared__ float tile[64][65];
        int j0 = (blk & 15) * 64;
        int k0 = (blk >> 4) * 64;
        for (int i = t; i < 4096; i += 256) {
            int r = i >> 6, c = i & 63;
            int k = k0 + c;
            tile[r][c] = (k < 432) ? W_ih[(size_t)(j0 + r) * 432 + k] : 0.f;
        }
        __syncthreads();
        for (int i = t; i < 4096; i += 256) {
            int r = i >> 6, c = i & 63;
            int k = k0 + r;
            if (k < 432) W_ih_T[(size_t)k * 1024 + j0 + c] = tile[c][r];
        }
    } else if (blk < 176) {
        // W_hh (1024x256) -> W_hh_T (256x1024)
        __shared__ float tile[64][65];
        int bb = blk - 112;
        int j0 = (bb & 15) * 64;
        int k0 = (bb >> 4) * 64;  // 4 k-tiles
        for (int i = t; i < 4096; i += 256) {
            int r = i >> 6, c = i & 63;
            tile[r][c] = W_hh[(size_t)(j0 + r) * 256 + k0 + c];
        }
        __syncthreads();
        for (int i = t; i < 4096; i += 256) {
            int r = i >> 6, c = i & 63;
            W_hh_T[(size_t)(k0 + r) * 1024 + j0 + c] = tile[c][r];
        }
    } else if (blk == 176) {
        // per-step bias: b_ih + b_hh + addr_emb[aid] @ W_addr.T  (W_ih cols 416..431)
        const int aids[7] = {0, 1, 4, 2, 3, 5, 6};
        for (int s = 0; s < 7; s++) {
            int aid = aids[s];
            for (int j = t; j < 1024; j += 256) {
                float v = b_ih[j] + b_hh[j];
                #pragma unroll
                for (int k = 0; k < 16; k++)
                    v += addr_emb[aid * 16 + k] * W_ih[(size_t)j * 432 + 416 + k];
                bias_all[s * 1024 + j] = v;
            }
        }
    } else if (blk == 177) {
        // pid_rows = pid_emb @ W_samp.T (3x1024), sid_rows (2x1024); W_ih cols 400..415
        for (int p = 0; p < 3; p++)
            for (int j = t; j < 1024; j += 256) {
                float v = 0.f;
                #pragma unroll
                for (int k = 0; k < 16; k++)
                    v += pid_emb[p * 16 + k] * W_ih[(size_t)j * 432 + 400 + k];
                pid_rows[p * 1024 + j] = v;
            }
        for (int p = 0; p < 2; p++)
            for (int j = t; j < 1024; j += 256) {
                float v = 0.f;
                #pragma unroll
                for (int k = 0; k < 16; k++)
                    v += sid_emb[p * 16 + k] * W_ih[(size_t)j * 432 + 400 + k];
                sid_rows[p * 1024 + j] = v;
            }
    } else {
        // transpose mlp_w2 (100x100) and mlp_w3 (16x100)
        for (int i = t; i < 10000; i += 256) {
            int o = i / 100, k = i % 100;
            w2t[k * 100 + o] = mlp_w2[i];
        }
        for (int i = t; i < 1600; i += 256) {
            int o = i / 100, k = i % 100;
            w3t[k * 16 + o] = mlp_w3[i];
        }
    }
}

// ---------------------------------------------------------------------------
// Conv encoder: one block per image. conv1 -> LDS(bf16), conv2 in registers,
// pool via LDS reuse -> obs_emb (B x 400)
// ---------------------------------------------------------------------------
__global__ __launch_bounds__(256) void conv_kernel(
    const float* __restrict__ obs, const float* __restrict__ w1,
    const float* __restrict__ b1, const float* __restrict__ w2,
    const float* __restrict__ b2, float* __restrict__ obs_emb)
{
    __shared__ __hip_bfloat16 c1[32][32][32];  // [ch][row][col], 64 KB
    int b = blockIdx.x;
    int t = threadIdx.x;
    const float* og = obs + (size_t)b * 4096;

    // conv1: thread = (c = t>>3, x-group of 4 cols), loop rows
    {
        int c = t >> 3;
        int x0 = (t & 7) * 4;
        float wv[9];
        #pragma unroll
        for (int k = 0; k < 9; k++) wv[k] = w1[c * 9 + k];
        float bb = b1[c];
        for (int r = 0; r < 32; r++) {
            float o4[4] = {bb, bb, bb, bb};
            #pragma unroll
            for (int dy = 0; dy < 3; dy++) {
                int R = 2 * r - 1 + dy;
                bool rok = (unsigned)R < 64u;
                float in9[9];
                #pragma unroll
                for (int j = 0; j < 9; j++) {
                    int C = 2 * x0 - 1 + j;
                    in9[j] = (rok && (unsigned)C < 64u) ? og[R * 64 + C] : 0.f;
                }
                #pragma unroll
                for (int xx = 0; xx < 4; xx++)
                    #pragma unroll
                    for (int dx = 0; dx < 3; dx++)
                        o4[xx] += wv[dy * 3 + dx] * in9[2 * xx + dx];
            }
            #pragma unroll
            for (int xx = 0; xx < 4; xx++)
                c1[c][r][x0 + xx] = __float2bfloat16(fmaxf(o4[xx], 0.f));
        }
    }
    __syncthreads();

    // conv2: thread = output position (y = t>>4, x = t&15), 16 oc accumulators
    float acc[16];
    {
        int y = t >> 4, x = t & 15;
        #pragma unroll
        for (int o = 0; o < 16; o++) acc[o] = b2[o];
        for (int ic = 0; ic < 32; ic++) {
            float p[9];
            #pragma unroll
            for (int dy = 0; dy < 3; dy++) {
                int R = 2 * y - 1 + dy;
                bool rok = (unsigned)R < 32u;
                #pragma unroll
                for (int dx = 0; dx < 3; dx++) {
                    int C = 2 * x - 1 + dx;
                    p[dy * 3 + dx] = (rok && (unsigned)C < 32u)
                                         ? __bfloat162float(c1[ic][R][C]) : 0.f;
                }
            }
            // weight index is wave-uniform -> scalar loads
            #pragma unroll
            for (int o = 0; o < 16; o++) {
                #pragma unroll
                for (int k = 0; k < 9; k++)
                    acc[o] += p[k] * w2[(o * 32 + ic) * 9 + k];
            }
        }
    }
    __syncthreads();

    // relu -> LDS (reuse c1 region as fp32 c2), then 3x3/9 avg pool -> obs_emb
    float* c2f = (float*)&c1[0][0][0];  // 16*16*16 fp32 = 16 KB
    {
        int y = t >> 4, x = t & 15;
        #pragma unroll
        for (int o = 0; o < 16; o++)
            c2f[(o * 16 + y) * 16 + x] = fmaxf(acc[o], 0.f);
    }
    __syncthreads();
    for (int p = t; p < 400; p += 256) {
        int c = p / 25, rem = p % 25, py = rem / 5, px = rem % 5;
        float s = 0.f;
        #pragma unroll
        for (int dy = 0; dy < 3; dy++)
            #pragma unroll
            for (int dx = 0; dx < 3; dx++)
                s += c2f[(c * 16 + 3 * py + dy) * 16 + 3 * px + dx];
        obs_emb[(size_t)b * 400 + p] = s * (1.f / 9.f);
    }
}

// ---------------------------------------------------------------------------
// obs_part = obs_emb (B x 400) @ W_obs.T -> (B x 1024). M-tile 16, 512 thr.
// ---------------------------------------------------------------------------
__global__ __launch_bounds__(512) void obs_gemm(
    const float* __restrict__ A, const float* __restrict__ Wt,
    float* __restrict__ outp)
{
    __shared__ float as_t[400][20];  // transposed A tile, padded (b128-aligned)
    __shared__ float Ws[8 * 1024];
    const int t = threadIdx.x;
    const int u = t & 255;
    const int mh = t >> 8;
    const int b0 = blockIdx.x * 16;
    float acc[8][4];
    #pragma unroll
    for (int m = 0; m < 8; m++)
        #pragma unroll
        for (int g = 0; g < 4; g++) acc[m][g] = 0.f;

    for (int i = t; i < 16 * 400; i += 512) {
        int r = i / 400, c = i % 400;
        as_t[c][r] = A[(size_t)(b0 + r) * 400 + c];
    }
    for (int kt = 0; kt < 50; kt++) {
        __syncthreads();
        int k0 = kt * 8;
        #pragma unroll
        for (int i = 0; i < 4; i++) {
            int f = t + i * 512;
            int rr = f >> 8, cc = f & 255;
            ((float4*)Ws)[f] = ((const float4*)(Wt + (size_t)(k0 + rr) * 1024))[cc];
        }
        __syncthreads();
        #pragma unroll
        for (int kk = 0; kk < 8; kk++) {
            float w0 = Ws[kk * 1024 + u];
            float w1 = Ws[kk * 1024 + u + 256];
            float w2 = Ws[kk * 1024 + u + 512];
            float w3 = Ws[kk * 1024 + u + 768];
            const float4* hp = (const float4*)&as_t[k0 + kk][mh * 8];
            float4 ha = hp[0], hb = hp[1];
            float hv[8] = {ha.x, ha.y, ha.z, ha.w, hb.x, hb.y, hb.z, hb.w};
            #pragma unroll
            for (int m = 0; m < 8; m++) {
                acc[m][0] += hv[m] * w0;
                acc[m][1] += hv[m] * w1;
                acc[m][2] += hv[m] * w2;
                acc[m][3] += hv[m] * w3;
            }
        }
    }
    #pragma unroll
    for (int m = 0; m < 8; m++) {
        size_t row = b0 + mh * 8 + m;
        #pragma unroll
        for (int g = 0; g < 4; g++)
            outp[row * 1024 + u + 256 * g] = acc[m][g];
    }
}

// ---------------------------------------------------------------------------
// Fused LSTM step: g = obs_part + bias_s + samp + h@W_hh.T, elementwise,
// optional head into d_out. Thread t owns gates {u, u+256, u+512, u+768}.
// SAMP: 0 none, 1 gather(samp_rows, samp_idx), 2 rp0_emb@W_samp.T (K=16)
// HEAD: 0 none, 1 logits(HEAD_N), 2 rp-pair (exp + eps)
// ---------------------------------------------------------------------------
template <int SAMP, int HEAD, int HEAD_N, bool HAS_GEMM, bool STORE_RP>
__global__ __launch_bounds__(512) void lstm_step(
    const float* __restrict__ h_in, const float* __restrict__ c_in,
    float* __restrict__ h_out, float* __restrict__ c_out,
    const float* __restrict__ obs_part, const float* __restrict__ bias_s,
    const float* __restrict__ samp_rows, const int* __restrict__ samp_idx,
    const float* __restrict__ rp0_emb, const float* __restrict__ WsampT,
    const float* __restrict__ Wt,
    const float* __restrict__ head_w, const float* __restrict__ head_b,
    const float* __restrict__ eps, float* __restrict__ out, int out_off,
    float* __restrict__ rp0_store)
{
    __shared__ float hs_t[256][20];  // h_in tile transposed [k][m], padded
    __shared__ float Ws[8 * 1024];   // W_hh_T k-slab; reused for head h-tile
    const int t = threadIdx.x;
    const int u = t & 255;
    const int mh = t >> 8;  // row half: rows mh*8 .. mh*8+7
    const int b0 = blockIdx.x * 16;

    float acc[8][4];
    #pragma unroll
    for (int m = 0; m < 8; m++) {
        int row = b0 + mh * 8 + m;
        int si = (SAMP == 1) ? samp_idx[row] : 0;
        #pragma unroll
        for (int g = 0; g < 4; g++) {
            int j = u + 256 * g;
            float v = obs_part[(size_t)row * 1024 + j] + bias_s[j];
            if (SAMP == 1) v += samp_rows[si * 1024 + j];
            acc[m][g] = v;
        }
    }
    if (SAMP == 2) {
        #pragma unroll
        for (int m = 0; m < 8; m++) {
            int row = b0 + mh * 8 + m;
            #pragma unroll
            for (int k = 0; k < 16; k++) {
                float e = rp0_emb[(size_t)row * 16 + k];
                #pragma unroll
                for (int g = 0; g < 4; g++)
                    acc[m][g] += e * WsampT[k * 1024 + u + 256 * g];
            }
        }
    }

    if (HAS_GEMM) {
        for (int i = t; i < 4096; i += 512) {
            int r = i >> 8, c = i & 255;
            hs_t[c][r] = h_in[(size_t)(b0 + r) * 256 + c];
        }
        for (int kt = 0; kt < 32; kt++) {
            __syncthreads();
            int k0 = kt * 8;
            #pragma unroll
            for (int i = 0; i < 4; i++) {
                int f = t + i * 512;
                int rr = f >> 8, cc = f & 255;
                ((float4*)Ws)[f] = ((const float4*)(Wt + (size_t)(k0 + rr) * 1024))[cc];
            }
            __syncthreads();
            #pragma unroll
            for (int kk = 0; kk < 8; kk++) {
                float w0 = Ws[kk * 1024 + u];
                float w1 = Ws[kk * 1024 + u + 256];
                float w2 = Ws[kk * 1024 + u + 512];
                float w3 = Ws[kk * 1024 + u + 768];
                const float4* hp = (const float4*)&hs_t[k0 + kk][mh * 8];
                float4 ha = hp[0], hb = hp[1];
                float hv[8] = {ha.x, ha.y, ha.z, ha.w, hb.x, hb.y, hb.z, hb.w};
                #pragma unroll
                for (int m = 0; m < 8; m++) {
                    acc[m][0] += hv[m] * w0;
                    acc[m][1] += hv[m] * w1;
                    acc[m][2] += hv[m] * w2;
                    acc[m][3] += hv[m] * w3;
                }
            }
        }
    }

    // LSTM elementwise: i,f,g,o all in this thread's registers
    float hval[8];
    #pragma unroll
    for (int m = 0; m < 8; m++) {
        size_t row = b0 + mh * 8 + m;
        float ci = HAS_GEMM ? c_in[row * 256 + u] : 0.f;
        float gi = acc[m][0], gf = acc[m][1], gg = acc[m][2], go = acc[m][3];
        float c2 = sigf(gf) * ci + sigf(gi) * tanh_fast(gg);
        float hv = sigf(go) * tanh_fast(c2);
        c_out[row * 256 + u] = c2;
        h_out[row * 256 + u] = hv;
        hval[m] = hv;
    }

    if (HEAD != 0) {
        __syncthreads();  // done reading Ws/hs_t
        float* hsh = Ws;  // 16 x 256 h tile
        #pragma unroll
        for (int m = 0; m < 8; m++) hsh[(mh * 8 + m) * 256 + u] = hval[m];
        __syncthreads();
        if (HEAD == 1) {
            if (t < 16 * HEAD_N) {
                int m = t & 15, o = t >> 4;
                float s = head_b[o];
                for (int k = 0; k < 256; k++)
                    s += hsh[m * 256 + k] * head_w[o * 256 + k];
                out[(size_t)(b0 + m) * OUT_W + out_off + o] = s;
            }
        } else {
            if (t < 32) {
                int m = t & 15, o = t >> 4;  // o in {0,1}
                float sa = head_b[o], sb = head_b[o + 2];
                for (int k = 0; k < 256; k++) {
                    float h = hsh[m * 256 + k];
                    sa += h * head_w[o * 256 + k];
                    sb += h * head_w[(o + 2) * 256 + k];
                }
                float val = sa + __expf(sb) * eps[(size_t)(b0 + m) * 2 + o];
                out[(size_t)(b0 + m) * OUT_W + out_off + o] = val;
                if (STORE_RP) rp0_store[(size_t)(b0 + m) * 2 + o] = val;
            }
        }
    }
}

// ---------------------------------------------------------------------------
// MLP: rp0 (B x 2) -> 100 -> 100 -> rp0_emb (B x 16), one block per row
// ---------------------------------------------------------------------------
__global__ __launch_bounds__(128) void mlp_kernel(
    const float* __restrict__ rp0, const float* __restrict__ w1,
    const float* __restrict__ b1, const float* __restrict__ w2t,
    const float* __restrict__ b2, const float* __restrict__ w3t,
    const float* __restrict__ b3, float* __restrict__ emb)
{
    __shared__ float z1[100], z2[100];
    int row = blockIdx.x, t = threadIdx.x;
    float r0 = rp0[(size_t)row * 2], r1 = rp0[(size_t)row * 2 + 1];
    if (t < 100) z1[t] = tanh_fast(b1[t] + w1[t * 2] * r0 + w1[t * 2 + 1] * r1);
    __syncthreads();
    if (t < 100) {
        float s = b2[t];
        for (int k = 0; k < 100; k++) s += w2t[k * 100 + t] * z1[k];
        z2[t] = tanh_fast(s);
    }
    __syncthreads();
    if (t < 16) {
        float s = b3[t];
        for (int k = 0; k < 100; k++) s += w3t[k * 16 + t] * z2[k];
        emb[(size_t)row * 16 + t] = s;
    }
}

// ---------------------------------------------------------------------------
extern "C" void kernel_launch(void* const* d_in, const int* in_sizes, int n_in,
                              void* d_out, int out_size, void* d_ws, size_t ws_size,
                              hipStream_t stream)
{
    const float* obs        = (const float*)d_in[0];
    const int*   program_id = (const int*)d_in[1];
    const int*   shape_id   = (const int*)d_in[2];
    const int*   shape_id_0 = (const int*)d_in[3];
    const int*   shape_id_1 = (const int*)d_in[4];
    const float* eps_rp     = (const float*)d_in[5];
    const float* eps_rp0    = (const float*)d_in[6];
    const float* eps_rp1    = (const float*)d_in[7];
    const float* conv1_w    = (const float*)d_in[8];
    const float* conv1_b    = (const float*)d_in[9];
    const float* conv2_w    = (const float*)d_in[10];
    const float* conv2_b    = (const float*)d_in[11];
    const float* mlp_w1     = (const float*)d_in[12];
    const float* mlp_b1     = (const float*)d_in[13];
    const float* mlp_w2     = (const float*)d_in[14];
    const float* mlp_b2     = (const float*)d_in[15];
    const float* mlp_w3     = (const float*)d_in[16];
    const float* mlp_b3     = (const float*)d_in[17];
    const float* W_ih       = (const float*)d_in[18];
    // 19: b_ih, 20: W_hh, 21: b_hh
    const float* b_ih       = (const float*)d_in[19];
    const float* W_hh       = (const float*)d_in[20];
    const float* b_hh       = (const float*)d_in[21];
    const float* addr_emb   = (const float*)d_in[22];
    const float* pid_emb    = (const float*)d_in[23];
    const float* sid_emb    = (const float*)d_in[24];
    const float* pid_ext_w  = (const float*)d_in[25];
    const float* pid_ext_b  = (const float*)d_in[26];
    const float* sid_ext_w  = (const float*)d_in[27];
    const float* sid_ext_b  = (const float*)d_in[28];
    const float* rp_ext_w   = (const float*)d_in[29];
    const float* rp_ext_b   = (const float*)d_in[30];
    float* out = (float*)d_out;

    // workspace layout (floats)
    float* ws = (float*)d_ws;
    size_t off = 0;
    float* W_ih_T   = ws + off; off += 432 * 1024;      // 442368
    float* W_hh_T   = ws + off; off += 256 * 1024;      // 262144
    float* bias_all = ws + off; off += 7 * 1024;
    float* pid_rows = ws + off; off += 3 * 1024;
    float* sid_rows = ws + off; off += 2 * 1024;
    float* obs_emb  = ws + off; off += (size_t)BATCH * 400;
    float* obs_part = ws + off; off += (size_t)BATCH * 1024;
    float* h0 = ws + off; off += (size_t)BATCH * 256;
    float* c0 = ws + off; off += (size_t)BATCH * 256;
    float* h1 = ws + off; off += (size_t)BATCH * 256;
    float* c1 = ws + off; off += (size_t)BATCH * 256;
    float* rp0      = ws + off; off += (size_t)BATCH * 2;
    float* rp0_emb  = ws + off; off += (size_t)BATCH * 16;
    float* w2t = ws + off; off += 10000;
    float* w3t = ws + off; off += 1600;
    float* WsampT = W_ih_T + (size_t)400 * 1024;  // rows 400..415 of W_ih_T

    prep_kernel<<<179, 256, 0, stream>>>(W_ih, W_hh, b_ih, b_hh, addr_emb,
                                         pid_emb, sid_emb, mlp_w2, mlp_w3,
                                         W_ih_T, W_hh_T, bias_all, pid_rows,
                                         sid_rows, w2t, w3t);
    conv_kernel<<<BATCH, 256, 0, stream>>>(obs, conv1_w, conv1_b, conv2_w,
                                           conv2_b, obs_emb);
    obs_gemm<<<BATCH / 16, 512, 0, stream>>>(obs_emb, W_ih_T, obs_part);

    // step0 (aid 0): h=c=0, head pid_logits (3) -> cols 0..2
    lstm_step<0, 1, 3, false, false><<<BATCH / 16, 512, 0, stream>>>(
        nullptr, nullptr, h0, c0, obs_part, bias_all + 0 * 1024,
        nullptr, nullptr, nullptr, nullptr, nullptr,
        pid_ext_w, pid_ext_b, nullptr, out, 0, nullptr);
    // step1 (aid 1): samp=pid_rows[program_id], h0->h1; head sid -> cols 3..4
    lstm_step<1, 1, 2, true, false><<<BATCH / 16, 512, 0, stream>>>(
        h0, c0, h1, c1, obs_part, bias_all + 1 * 1024,
        pid_rows, program_id, nullptr, nullptr, W_hh_T,
        sid_ext_w, sid_ext_b, nullptr, out, 3, nullptr);
    // step2 (aid 4): samp=sid_rows[shape_id], h1->h1 in-place; head rp_b0 -> cols 5..6
    lstm_step<1, 2, 0, true, false><<<BATCH / 16, 512, 0, stream>>>(
        h1, c1, h1, c1, obs_part, bias_all + 2 * 1024,
        sid_rows, shape_id, nullptr, nullptr, W_hh_T,
        rp_ext_w, rp_ext_b, eps_rp, out, 5, nullptr);
    // step1b (aid 2): samp=pid_rows[program_id], h0->h0 in-place; head sid0 -> cols 7..8
    lstm_step<1, 1, 2, true, false><<<BATCH / 16, 512, 0, stream>>>(
        h0, c0, h0, c0, obs_part, bias_all + 3 * 1024,
        pid_rows, program_id, nullptr, nullptr, W_hh_T,
        sid_ext_w, sid_ext_b, nullptr, out, 7, nullptr);
    // step2b (aid 3): samp=sid_rows[shape_id_0]; head sid1 -> cols 9..10
    lstm_step<1, 1, 2, true, false><<<BATCH / 16, 512, 0, stream>>>(
        h0, c0, h0, c0, obs_part, bias_all + 4 * 1024,
        sid_rows, shape_id_0, nullptr, nullptr, W_hh_T,
        sid_ext_w, sid_ext_b, nullptr, out, 9, nullptr);
    // step3b (aid 5): samp=sid_rows[shape_id_1]; head rp0 -> cols 11..12 (+store)
    lstm_step<1, 2, 0, true, true><<<BATCH / 16, 512, 0, stream>>>(
        h0, c0, h0, c0, obs_part, bias_all + 5 * 1024,
        sid_rows, shape_id_1, nullptr, nullptr, W_hh_T,
        rp_ext_w, rp_ext_b, eps_rp0, out, 11, rp0);
    mlp_kernel<<<BATCH, 128, 0, stream>>>(rp0, mlp_w1, mlp_b1, w2t, mlp_b2,
                                          w3t, mlp_b3, rp0_emb);
    // step4b (aid 6): samp = rp0_emb @ W_samp.T; head rp1 -> cols 13..14
    lstm_step<2, 2, 0, true, false><<<BATCH / 16, 512, 0, stream>>>(
        h0, c0, h1, c1, obs_part, bias_all + 6 * 1024,
        nullptr, nullptr, rp0_emb, WsampT, W_hh_T,
        rp_ext_w, rp_ext_b, eps_rp1, out, 13, nullptr);
}